// Round 5
// baseline (254.732 us; speedup 1.0000x reference)
//
#include <hip/hip_runtime.h>
#include <hip/hip_bf16.h>

#define G 160
#define GM1 159
#define KD 128    // 16 k * 8 d complex channels
#define KP 320    // doubled K (re/im interleaved)
#define PLANE_U 3276800   // uints per plane of B/T (128*160*160)
#define NBUCK 4096        // 2^12 morton buckets (4 bits/axis)
#define TWO_PI_F 6.28318530717958647692f

// T is scaled by TSCALE at stage1 (folded into alpha) so f16 T values sit in
// the normal range (~5e-3 instead of ~2e-5 subnormal); sampler undoes it.
#define TSCALE 256.0f
#define TSCALE_INV 0.00390625f

typedef __attribute__((ext_vector_type(8))) short bf16x8;   // 4 VGPRs, 8 bf16
typedef __attribute__((ext_vector_type(4))) float f32x4;
typedef _Float16 half2t __attribute__((ext_vector_type(2)));
typedef __fp16 fp16x2 __attribute__((ext_vector_type(2)));

__device__ __forceinline__ unsigned short f2bf(float x) {
    unsigned u = __float_as_uint(x);
    unsigned r = (u + 0x7FFFu + ((u >> 16) & 1u)) >> 16;   // RNE
    return (unsigned short)r;
}
__device__ __forceinline__ unsigned int packbf(float re, float im) {
    union { __hip_bfloat162 h; unsigned int u; } cv;
    cv.h = __float22bfloat162_rn(make_float2(re, im));      // v_cvt_pk_bf16_f32
    return cv.u;
}
// pack (a,b) f32 -> f16x2 in one v_cvt_pkrtz_f16_f32 (as half2t via bitcast)
__device__ __forceinline__ half2t cvtpk(float a, float b) {
    union { fp16x2 f; half2t h; } cv;
    cv.f = __builtin_amdgcn_cvt_pkrtz(a, b);
    return cv.h;
}
__device__ __forceinline__ unsigned int packh(float re, float im) {
    union { fp16x2 f; unsigned int u; } cv;
    cv.f = __builtin_amdgcn_cvt_pkrtz(re, im);
    return cv.u;
}
__device__ __forceinline__ half2t u2h2(unsigned int u) {
    union { unsigned int u; half2t h; } cv;
    cv.u = u;
    return cv.h;
}
// 2-way f16 dot with f32 accumulate: acc += a.x*b.x + a.y*b.y
__device__ __forceinline__ float fdot2h(half2t a, half2t b, float acc) {
#if __has_builtin(__builtin_amdgcn_fdot2)
    return __builtin_amdgcn_fdot2(a, b, acc, false);
#else
    return acc + (float)a.x * (float)b.x + (float)a.y * (float)b.y;
#endif
}
// Wim fragment uint from Wre fragment uint: (c,-s) -> (s,c)
__device__ __forceinline__ unsigned int wim_of(unsigned int u) {
    return ((u << 16) | (u >> 16)) ^ 0x00008000u;
}
__device__ __forceinline__ unsigned int rot16(unsigned int u) {
    return (u << 16) | (u >> 16);
}
__device__ __forceinline__ unsigned part1by2(unsigned x) {
    x &= 0x3FF;
    x = (x | (x << 16)) & 0xFF0000FFu;
    x = (x | (x << 8))  & 0x0300F00Fu;
    x = (x | (x << 4))  & 0x030C30C3u;
    x = (x | (x << 2))  & 0x09249249u;
    return x;
}
__device__ __forceinline__ unsigned morton_key(float x, float y, float z) {
    int cx = min(max((int)((x + 1.0f) * 8.0f), 0), 15);
    int cy = min(max((int)((y + 1.0f) * 8.0f), 0), 15);
    int cz = min(max((int)((z + 1.0f) * 8.0f), 0), 15);
    return part1by2(cx) | (part1by2(cy) << 1) | (part1by2(cz) << 2);   // 12 bits
}

// ---------------------------------------------------------------------------
// Fused preprocessing: [0,16) zero counts | [16,216) W init | [216,1816) packw
// ---------------------------------------------------------------------------
__global__ __launch_bounds__(256) void k_prep(
    const float* __restrict__ Pw_re, const float* __restrict__ Pw_im,
    unsigned int* __restrict__ Apw, unsigned short* __restrict__ Wre,
    unsigned int* __restrict__ counts)
{
    __shared__ unsigned int sT[64 * 33];
    int b = blockIdx.x;
    int tid = threadIdx.x;
    if (b < 16) {
        counts[b * 256 + tid] = 0;
        return;
    }
    if (b < 216) {
        int idx = (b - 16) * 256 + tid;   // < 51200
        int r = idx / KP, kp = idx - r * KP;
        int q = kp >> 1;
        int m = (r * q) % G;
        float th = (float)m * (TWO_PI_F / (float)G);
        float s, c;
        __sincosf(th, &s, &c);
        Wre[idx] = f2bf(((kp & 1) == 0 ? c : -s) * (1.0f / (float)G));
        return;
    }
    // packw: Pw (k,y,x,d) [204800, 8, 1280, 1] -> Apw[m=(k*8+d)*160+y][q=x]
    int b2 = b - 216;                     // 0..1599
    int k  = b2 / 100;
    int rem = b2 - k * 100;
    int pc = rem / 5;
    int q0 = (rem - pc * 5) * 32;

    int i = tid & 63, qo = tid >> 6;
    size_t base = (size_t)k * 204800 + (size_t)pc * 64 + i;
    #pragma unroll
    for (int qc = 0; qc < 8; qc++) {
        int q = q0 + qo * 8 + qc;
        float r  = Pw_re[base + (size_t)q * 1280];
        float im = Pw_im[base + (size_t)q * 1280];
        sT[i * 33 + qo * 8 + qc] = packbf(r, im);
    }
    __syncthreads();
    int qp = tid & 31, mo = tid >> 5;
    #pragma unroll
    for (int mc = 0; mc < 8; mc++) {
        int m = (k * 8 + mo) * G + pc * 8 + mc;
        Apw[(size_t)m * G + q0 + qp] = sT[(mc * 8 + mo) * 33 + qp];
    }
}

// ---------------------------------------------------------------------------
// Morton counting sort: hist -> scan -> scatter(sorted float4)
// ---------------------------------------------------------------------------
__global__ __launch_bounds__(256) void k_hist(
    const float* __restrict__ xyz, const float* __restrict__ bound,
    unsigned int* __restrict__ counts, int N)
{
    int i = blockIdx.x * blockDim.x + threadIdx.x;
    if (i >= N) return;
    float invb = 1.0f / bound[0];
    float x = xyz[3 * i + 0] * invb;
    float y = xyz[3 * i + 1] * invb;
    float z = xyz[3 * i + 2] * invb;
    atomicAdd(&counts[morton_key(x, y, z)], 1u);
}

// Shuffle-based scan: wave-scan (no barriers) + 16-wave LDS combine.
__global__ __launch_bounds__(1024) void k_scan(
    const unsigned int* __restrict__ counts,
    unsigned int* __restrict__ cursors)
{
    __shared__ unsigned int ws[16];
    int t = threadIdx.x;
    int lane = t & 63, wid = t >> 6;
    unsigned int local[4];
    unsigned int s = 0;
    #pragma unroll
    for (int i = 0; i < 4; i++) { local[i] = counts[t * 4 + i]; s += local[i]; }
    unsigned int sl = s;                    // own group-of-4 sum
    #pragma unroll
    for (int off = 1; off < 64; off <<= 1) {
        unsigned int v = __shfl_up(s, off, 64);
        if (lane >= off) s += v;            // inclusive wave scan
    }
    if (lane == 63) ws[wid] = s;
    __syncthreads();
    if (t < 16) {
        unsigned int x = ws[t];
        #pragma unroll
        for (int off = 1; off < 16; off <<= 1) {
            unsigned int v = __shfl_up(x, off, 64);
            if (t >= off) x += v;
        }
        ws[t] = x;                          // inclusive over wave totals
    }
    __syncthreads();
    unsigned int run = s - sl + (wid > 0 ? ws[wid - 1] : 0u);
    #pragma unroll
    for (int i = 0; i < 4; i++) { cursors[t * 4 + i] = run; run += local[i]; }
}

__global__ __launch_bounds__(256) void k_scatter(
    const float* __restrict__ xyz, const float* __restrict__ bound,
    unsigned int* __restrict__ cursors, float4* __restrict__ sxyz, int N)
{
    int i = blockIdx.x * blockDim.x + threadIdx.x;
    if (i >= N) return;
    float invb = 1.0f / bound[0];
    float x = xyz[3 * i + 0] * invb;
    float y = xyz[3 * i + 1] * invb;
    float z = xyz[3 * i + 2] * invb;
    unsigned int pos = atomicAdd(&cursors[morton_key(x, y, z)], 1u);
    sxyz[pos] = make_float4(x, y, z, __int_as_float(i));
}

// ---------------------------------------------------------------------------
// Stage 1: B[m=(kd,p)][l] = alpha * sum_q A*W[l][q].
// R4 finding: only 1920 waves at 2 m-tiles/wave (<2 waves/SIMD) — the work
// decomposition itself capped occupancy; and 100KB W LDS forced 1 block/CU.
// Fix: 1 m-tile/wave (3840 waves, 480 blocks) + conjugate-folded W LDS:
// W[160-l][q] = conj(W[l][q]), so store only l-tiles 0..5 (60KB) and derive
// tiles 6..9 per-lane: src tile = (col==0 ? 10-lt : 9-lt), src col =
// (col==0 ? 0 : 16-col); cr = u ^ 0x80000000 (flip -s half), ci = rot16(u)
// (wim_of's ^0x8000 cancels against conjugation). 2 blocks/CU resident.
// W-from-LDS (~12cy) means 4 MFMA chains cover load latency (R3's 4-chain
// failure was W-from-L2 at ~200cy).
// ---------------------------------------------------------------------------
__global__ __launch_bounds__(512, 4) void k_stage1(
    const float* __restrict__ Pu_re, const float* __restrict__ Pu_im,
    const float* __restrict__ Pv_re, const float* __restrict__ Pv_im,
    const unsigned int* __restrict__ Apw,
    const float* __restrict__ alpha_params,
    const unsigned short* __restrict__ Wre,
    unsigned int* __restrict__ Bfrag)
{
    __shared__ __align__(16) unsigned short sW[30720];   // 60 KB: tiles 0..5
    int tid = threadIdx.x;
    int w = tid >> 6, lane = tid & 63;
    int col = lane & 15, g4 = lane >> 4;
    int gw = blockIdx.x * 8 + w;          // 0..3839 wave-tasks, 1 m-tile each
    int plane = gw / 1280;
    int mtl = gw - plane * 1280;          // plane-local m-tile idx

    // stage W permuted fragments, l-tiles 0..5 only:
    // chunk=(lt*10+t)*64+ln holds Wre frag of (lt,t,ln)
    for (int chunk = tid; chunk < 3840; chunk += 512) {
        int lt = chunk / 640;
        int r  = chunk - lt * 640;
        int t  = r >> 6;
        int ln = r & 63;
        int c  = ln & 15, g = ln >> 4;
        uint4 v = *(const uint4*)&Wre[(lt * 16 + c) * KP + t * 32 + g * 8];
        *(uint4*)&sW[chunk * 8] = v;
    }

    float ap = alpha_params[0];
    float bxv = 10.0f * ap;
    float alpha = (bxv > 1.0f) ? ap : log1pf(expf(fminf(bxv, 1.0f))) * 0.1f;
    alpha *= TSCALE;

    bf16x8 afr[10];
    if (plane == 2) {
        const unsigned int* a2 = Apw + (size_t)(mtl * 16 + col) * G + g4 * 4;
        #pragma unroll
        for (int t = 0; t < 10; t++) {
            union { uint4 u; bf16x8 b; } cv;
            cv.u = *(const uint4*)(a2 + t * 16);
            afr[t] = cv.b;
        }
    } else {
        const float *Ar, *Ai; int sd_, sp_;
        if (plane == 0) { Ar = Pu_re; Ai = Pu_im; sd_ = 25600; sp_ = 160; }
        else            { Ar = Pv_re; Ai = Pv_im; sd_ = 160;   sp_ = 1280; }
        int m = mtl * 16 + col;
        int k = m / 1280; int rm = m - k * 1280;
        int d = rm / 160; int p = rm - d * 160;
        size_t abase = (size_t)k * 204800 + (size_t)d * sd_ + (size_t)p * sp_ + g4 * 4;
        #pragma unroll
        for (int t = 0; t < 10; t++) {
            float4 vr = *(const float4*)(Ar + abase + t * 16);
            float4 vi = *(const float4*)(Ai + abase + t * 16);
            union { unsigned int u[4]; bf16x8 b; } cv;
            cv.u[0] = packbf(vr.x, vi.x); cv.u[1] = packbf(vr.y, vi.y);
            cv.u[2] = packbf(vr.z, vi.z); cv.u[3] = packbf(vr.w, vi.w);
            afr[t] = cv.b;
        }
    }

    __syncthreads();

    unsigned int* Bpl = Bfrag + (size_t)plane * PLANE_U;
    int kd = mtl / 10, pt = mtl - kd * 10;

    // direct l-tiles 0..5 (pairs 0,1,2)
    #pragma unroll
    for (int lt2 = 0; lt2 < 3; lt2++) {
        int ltA = lt2 * 2, ltB = lt2 * 2 + 1;
        f32x4 arA = (f32x4)(0.f), aiA = (f32x4)(0.f);
        f32x4 arB = (f32x4)(0.f), aiB = (f32x4)(0.f);
        const unsigned short* wpA = &sW[(ltA * 640 + lane) * 8];
        const unsigned short* wpB = &sW[(ltB * 640 + lane) * 8];
        #pragma unroll
        for (int t = 0; t < 10; t++) {
            union { uint4 u; bf16x8 b; } crA, ciA, crB, ciB;
            crA.u = *(const uint4*)(wpA + t * 512);
            crB.u = *(const uint4*)(wpB + t * 512);
            ciA.u.x = wim_of(crA.u.x); ciA.u.y = wim_of(crA.u.y);
            ciA.u.z = wim_of(crA.u.z); ciA.u.w = wim_of(crA.u.w);
            ciB.u.x = wim_of(crB.u.x); ciB.u.y = wim_of(crB.u.y);
            ciB.u.z = wim_of(crB.u.z); ciB.u.w = wim_of(crB.u.w);
            arA = __builtin_amdgcn_mfma_f32_16x16x32_bf16(afr[t], crA.b, arA, 0, 0, 0);
            aiA = __builtin_amdgcn_mfma_f32_16x16x32_bf16(afr[t], ciA.b, aiA, 0, 0, 0);
            arB = __builtin_amdgcn_mfma_f32_16x16x32_bf16(afr[t], crB.b, arB, 0, 0, 0);
            aiB = __builtin_amdgcn_mfma_f32_16x16x32_bf16(afr[t], ciB.b, aiB, 0, 0, 0);
        }
        uint4 o;
        o.x = packbf(alpha * arA[0], alpha * aiA[0]);
        o.y = packbf(alpha * arA[1], alpha * aiA[1]);
        o.z = packbf(alpha * arA[2], alpha * aiA[2]);
        o.w = packbf(alpha * arA[3], alpha * aiA[3]);
        *(uint4*)(Bpl + (size_t)(kd * 10 + ltA) * 2560 + pt * 256 + lane * 4) = o;
        o.x = packbf(alpha * arB[0], alpha * aiB[0]);
        o.y = packbf(alpha * arB[1], alpha * aiB[1]);
        o.z = packbf(alpha * arB[2], alpha * aiB[2]);
        o.w = packbf(alpha * arB[3], alpha * aiB[3]);
        *(uint4*)(Bpl + (size_t)(kd * 10 + ltB) * 2560 + pt * 256 + lane * 4) = o;
    }

    // derived l-tiles 6..9 (pairs 3,4): row l = conj(row 160-l)
    #pragma unroll
    for (int lt2 = 3; lt2 < 5; lt2++) {
        int ltA = lt2 * 2, ltB = lt2 * 2 + 1;
        f32x4 arA = (f32x4)(0.f), aiA = (f32x4)(0.f);
        f32x4 arB = (f32x4)(0.f), aiB = (f32x4)(0.f);
        int stA = (col == 0) ? (10 - ltA) : (9 - ltA);
        int stB = (col == 0) ? (10 - ltB) : (9 - ltB);
        int sc  = (col == 0) ? 0 : (16 - col);
        const unsigned short* wpA = &sW[(stA * 640 + g4 * 16 + sc) * 8];
        const unsigned short* wpB = &sW[(stB * 640 + g4 * 16 + sc) * 8];
        #pragma unroll
        for (int t = 0; t < 10; t++) {
            union { uint4 u; bf16x8 b; } crA, ciA, crB, ciB;
            uint4 uA = *(const uint4*)(wpA + t * 512);
            uint4 uB = *(const uint4*)(wpB + t * 512);
            // conj: cr = u ^ 0x80000000 ; ci = wim_of(conj) = rot16(u)
            crA.u.x = uA.x ^ 0x80000000u; crA.u.y = uA.y ^ 0x80000000u;
            crA.u.z = uA.z ^ 0x80000000u; crA.u.w = uA.w ^ 0x80000000u;
            ciA.u.x = rot16(uA.x); ciA.u.y = rot16(uA.y);
            ciA.u.z = rot16(uA.z); ciA.u.w = rot16(uA.w);
            crB.u.x = uB.x ^ 0x80000000u; crB.u.y = uB.y ^ 0x80000000u;
            crB.u.z = uB.z ^ 0x80000000u; crB.u.w = uB.w ^ 0x80000000u;
            ciB.u.x = rot16(uB.x); ciB.u.y = rot16(uB.y);
            ciB.u.z = rot16(uB.z); ciB.u.w = rot16(uB.w);
            arA = __builtin_amdgcn_mfma_f32_16x16x32_bf16(afr[t], crA.b, arA, 0, 0, 0);
            aiA = __builtin_amdgcn_mfma_f32_16x16x32_bf16(afr[t], ciA.b, aiA, 0, 0, 0);
            arB = __builtin_amdgcn_mfma_f32_16x16x32_bf16(afr[t], crB.b, arB, 0, 0, 0);
            aiB = __builtin_amdgcn_mfma_f32_16x16x32_bf16(afr[t], ciB.b, aiB, 0, 0, 0);
        }
        uint4 o;
        o.x = packbf(alpha * arA[0], alpha * aiA[0]);
        o.y = packbf(alpha * arA[1], alpha * aiA[1]);
        o.z = packbf(alpha * arA[2], alpha * aiA[2]);
        o.w = packbf(alpha * arA[3], alpha * aiA[3]);
        *(uint4*)(Bpl + (size_t)(kd * 10 + ltA) * 2560 + pt * 256 + lane * 4) = o;
        o.x = packbf(alpha * arB[0], alpha * aiB[0]);
        o.y = packbf(alpha * arB[1], alpha * aiB[1]);
        o.z = packbf(alpha * arB[2], alpha * aiB[2]);
        o.w = packbf(alpha * arB[3], alpha * aiB[3]);
        *(uint4*)(Bpl + (size_t)(kd * 10 + ltB) * 2560 + pt * 256 + lane * 4) = o;
    }
}

// ---------------------------------------------------------------------------
// Stage 2: T[j][l][kd] = sum_p W[j][p]*B[kd][p][l].
// Block = (kd-octet, l-tile, plane), 640 thr = 10 waves = 10 j-tiles.
// B octet staged once into 80KB LDS; W A-frags register-hoisted.
// T packed f16 (re,im) per uint — consumed by v_dot2_f32_f16 in sampler.
// ---------------------------------------------------------------------------
__global__ __launch_bounds__(640) void k_stage2(
    const unsigned int* __restrict__ Bfrag,
    const unsigned short* __restrict__ Wre,
    unsigned int* __restrict__ Tall)
{
    __shared__ __align__(16) unsigned int sB[20480];   // 80 KB: 8 kd x 2560
    int tid = threadIdx.x;
    int w = tid >> 6, lane = tid & 63;
    int col = lane & 15, g4 = lane >> 4;
    int kdo = blockIdx.x;
    int lt  = blockIdx.y;
    int plane = blockIdx.z;

    const unsigned int* Bp = Bfrag + (size_t)plane * PLANE_U;
    #pragma unroll
    for (int i = 0; i < 8; i++) {
        uint4 v = *(const uint4*)(Bp + ((size_t)(kdo * 8 + i) * 10 + lt) * 2560 + tid * 4);
        *(uint4*)(sB + i * 2560 + tid * 4) = v;
    }

    bf16x8 wfr[10];
    const unsigned short* wp = &Wre[(w * 16 + col) * KP + g4 * 8];
    #pragma unroll
    for (int t = 0; t < 10; t++)
        wfr[t] = *(const bf16x8*)(wp + t * 32);

    __syncthreads();

    f32x4 ar[8], ai[8];
    #pragma unroll
    for (int i = 0; i < 8; i++) { ar[i] = (f32x4)(0.f); ai[i] = (f32x4)(0.f); }

    #pragma unroll
    for (int t = 0; t < 10; t++) {
        union { bf16x8 b; uint4 u; } cr, ci;
        cr.b = wfr[t];
        ci.u.x = wim_of(cr.u.x); ci.u.y = wim_of(cr.u.y);
        ci.u.z = wim_of(cr.u.z); ci.u.w = wim_of(cr.u.w);
        #pragma unroll
        for (int kq = 0; kq < 8; kq++) {
            bf16x8 bf = *(const bf16x8*)&sB[kq * 2560 + (t * 64 + lane) * 4];
            ar[kq] = __builtin_amdgcn_mfma_f32_16x16x32_bf16(cr.b, bf, ar[kq], 0, 0, 0);
            ai[kq] = __builtin_amdgcn_mfma_f32_16x16x32_bf16(ci.b, bf, ai[kq], 0, 0, 0);
        }
    }

    unsigned int* Tp = Tall + (size_t)plane * PLANE_U;
    #pragma unroll
    for (int reg = 0; reg < 4; reg++) {
        int j = w * 16 + g4 * 4 + reg;
        int l = lt * 16 + col;
        uint4 o0, o1;
        o0.x = packh(ar[0][reg], ai[0][reg]);
        o0.y = packh(ar[1][reg], ai[1][reg]);
        o0.z = packh(ar[2][reg], ai[2][reg]);
        o0.w = packh(ar[3][reg], ai[3][reg]);
        o1.x = packh(ar[4][reg], ai[4][reg]);
        o1.y = packh(ar[5][reg], ai[5][reg]);
        o1.z = packh(ar[6][reg], ai[6][reg]);
        o1.w = packh(ar[7][reg], ai[7][reg]);
        size_t ta = ((size_t)(j * G + l)) * KD + kdo * 8;
        *(uint4*)(Tp + ta)     = o0;
        *(uint4*)(Tp + ta + 4) = o1;
    }
}

// ---------------------------------------------------------------------------
// Sampler: 16 lanes/point, lane = k. Phase-split: all 3 planes' addresses,
// all 24 uint4 loads in flight, then math (PROVEN R7 load path).
// Math: per-corner f16 dot2 chains — each T uint is a (re,im) half2 consumed
// directly by v_dot2_f32_f16 against (C'_d, -S'_d) f16 pairs.
// ---------------------------------------------------------------------------
__device__ __forceinline__ void plane_addr(const unsigned int* __restrict__ T,
    float gy, float gx, int k, const unsigned int** cp, float* wv)
{
    float iy = (gy + 1.0f) * (0.5f * (float)GM1);
    float ix = (gx + 1.0f) * (0.5f * (float)GM1);
    float iy0f = floorf(iy), ix0f = floorf(ix);
    float wy = iy - iy0f, wx = ix - ix0f;
    int iy0 = (int)iy0f, ix0 = (int)ix0f;
    int iy1 = min(iy0 + 1, GM1), ix1 = min(ix0 + 1, GM1);
    iy0 = max(min(iy0, GM1), 0); ix0 = max(min(ix0, GM1), 0);
    iy1 = max(iy1, 0); ix1 = max(ix1, 0);
    cp[0] = &T[(size_t)(iy0 * G + ix0) * KD + k * 8];
    cp[1] = &T[(size_t)(iy0 * G + ix1) * KD + k * 8];
    cp[2] = &T[(size_t)(iy1 * G + ix0) * KD + k * 8];
    cp[3] = &T[(size_t)(iy1 * G + ix1) * KD + k * 8];
    wv[0] = (1.f - wx) * (1.f - wy);
    wv[1] = wx * (1.f - wy);
    wv[2] = (1.f - wx) * wy;
    wv[3] = wx * wy;
}

__device__ __forceinline__ float plane_math(const uint4* va, const uint4* vb,
                                            const float* wv, float fc)
{
    float s1v, c1v;
    __sincosf(TWO_PI_F * fc, &s1v, &c1v);
    // trig weights (C'_d, -S'_d) as f16 pairs; d=0: (1,0); d>=1: (2cd, -2sd)
    half2t tw[8];
    tw[0] = u2h2(0x00003C00u);            // (1.0h, 0.0h)
    float cd = c1v, sd = s1v;
    tw[1] = cvtpk(cd + cd, -(sd + sd));
    #pragma unroll
    for (int d = 2; d < 8; d++) {
        float t2 = cd + cd;
        float cn = __builtin_fmaf(t2, cd, -1.0f);
        float sn = t2 * sd;
        cd = cn; sd = sn;
        tw[d] = cvtpk(cd + cd, -(sd + sd));
    }
    const unsigned int* a0 = (const unsigned int*)&va[0];
    const unsigned int* a1 = (const unsigned int*)&va[1];
    const unsigned int* a2 = (const unsigned int*)&va[2];
    const unsigned int* a3 = (const unsigned int*)&va[3];
    const unsigned int* b0 = (const unsigned int*)&vb[0];
    const unsigned int* b1 = (const unsigned int*)&vb[1];
    const unsigned int* b2 = (const unsigned int*)&vb[2];
    const unsigned int* b3 = (const unsigned int*)&vb[3];
    float d0 = 0.f, d1 = 0.f, d2 = 0.f, d3 = 0.f;   // 4 independent chains
    #pragma unroll
    for (int d = 0; d < 4; d++) {
        half2t t = tw[d];
        d0 = fdot2h(u2h2(a0[d]), t, d0);
        d1 = fdot2h(u2h2(a1[d]), t, d1);
        d2 = fdot2h(u2h2(a2[d]), t, d2);
        d3 = fdot2h(u2h2(a3[d]), t, d3);
    }
    #pragma unroll
    for (int d = 0; d < 4; d++) {
        half2t t = tw[d + 4];
        d0 = fdot2h(u2h2(b0[d]), t, d0);
        d1 = fdot2h(u2h2(b1[d]), t, d1);
        d2 = fdot2h(u2h2(b2[d]), t, d2);
        d3 = fdot2h(u2h2(b3[d]), t, d3);
    }
    float acc = wv[0] * d0;
    acc = __builtin_fmaf(wv[1], d1, acc);
    acc = __builtin_fmaf(wv[2], d2, acc);
    acc = __builtin_fmaf(wv[3], d3, acc);
    return acc;
}

__global__ __launch_bounds__(256, 3) void k_sample(
    const float4* __restrict__ sxyz,
    const unsigned int* __restrict__ Tu, const unsigned int* __restrict__ Tv,
    const unsigned int* __restrict__ Tw,
    float* __restrict__ out, int N)
{
    int tid = threadIdx.x;
    int k = tid & 15;
    int nblocks = (N + 15) / 16;
    int seg = blockIdx.x & 7;
    int segblocks = nblocks >> 3;                 // N multiple of 128
    int pid = (seg * segblocks + (blockIdx.x >> 3)) * 16 + (tid >> 4);
    if (pid >= N) return;

    float4 pw = sxyz[pid];
    int n = __float_as_int(pw.w);
    float x = pw.x, y = pw.y, z = pw.z;

    const unsigned int* cp[3][4];
    float wv[3][4];
    plane_addr(Tu, y, z, k, cp[0], wv[0]);
    plane_addr(Tv, x, z, k, cp[1], wv[1]);
    plane_addr(Tw, y, x, k, cp[2], wv[2]);

    uint4 va[3][4], vb[3][4];
    #pragma unroll
    for (int pl = 0; pl < 3; pl++)
        #pragma unroll
        for (int c = 0; c < 4; c++) {
            va[pl][c] = *(const uint4*)cp[pl][c];
            vb[pl][c] = *(const uint4*)(cp[pl][c] + 4);
        }

    float acc = plane_math(va[0], vb[0], wv[0], (x + 1.0f) * 0.5f)
              + plane_math(va[1], vb[1], wv[1], (y + 1.0f) * 0.5f)
              + plane_math(va[2], vb[2], wv[2], (z + 1.0f) * 0.5f);
    out[n * 16 + k] = acc * TSCALE_INV;
}

// ---------------------------------------------------------------------------
extern "C" void kernel_launch(void* const* d_in, const int* in_sizes, int n_in,
                              void* d_out, int out_size, void* d_ws, size_t ws_size,
                              hipStream_t stream) {
    const float* xyz          = (const float*)d_in[0];
    const float* bound        = (const float*)d_in[1];
    const float* alpha_params = (const float*)d_in[2];
    const float* Pu_re = (const float*)d_in[3];
    const float* Pu_im = (const float*)d_in[4];
    const float* Pv_re = (const float*)d_in[5];
    const float* Pv_im = (const float*)d_in[6];
    const float* Pw_re = (const float*)d_in[7];
    const float* Pw_im = (const float*)d_in[8];
    float* out = (float*)d_out;
    int N = in_sizes[0] / 3;

    // ws: Wre 100K | Apw 12.5M | Bfrag 37.5M | T 37.5M | counts 16K |
    //     cursors 16K | sxyz 2M
    char* ws = (char*)d_ws;
    unsigned short* Wre  = (unsigned short*)(ws);
    unsigned int*   Apw  = (unsigned int*)(ws + 102400);
    unsigned int*   Bfr  = (unsigned int*)(ws + 102400 + 13107200);
    unsigned int*   Tall = (unsigned int*)(ws + 102400 + 13107200 + 39321600);
    char*           ws2  = ws + 102400 + 13107200 + 39321600 + 39321600;
    unsigned int*   counts  = (unsigned int*)(ws2);
    unsigned int*   cursors = (unsigned int*)(ws2 + 16384);
    float4*         sxyz    = (float4*)(ws2 + 32768);
    unsigned int*   Tu   = Tall;
    unsigned int*   Tv   = Tall + (size_t)PLANE_U;
    unsigned int*   Tw   = Tall + (size_t)2 * PLANE_U;

    // fused prep: zero counts + W table + Pw pack
    k_prep<<<1816, 256, 0, stream>>>(Pw_re, Pw_im, Apw, Wre, counts);
    // sort chain
    k_hist<<<(N + 255) / 256, 256, 0, stream>>>(xyz, bound, counts, N);
    k_scan<<<1, 1024, 0, stream>>>(counts, cursors);
    k_scatter<<<(N + 255) / 256, 256, 0, stream>>>(xyz, bound, cursors, sxyz, N);
    // DFT pipeline
    k_stage1<<<480, 512, 0, stream>>>(Pu_re, Pu_im, Pv_re, Pv_im, Apw,
                                      alpha_params, Wre, Bfr);
    k_stage2<<<dim3(16, 10, 3), 640, 0, stream>>>(Bfr, Wre, Tall);
    // sampler
    k_sample<<<(N + 15) / 16, 256, 0, stream>>>(sxyz, Tu, Tv, Tw, out, N);
}

// Round 6
// 248.439 us; speedup vs baseline: 1.0253x; 1.0253x over previous
//
#include <hip/hip_runtime.h>
#include <hip/hip_bf16.h>

#define G 160
#define GM1 159
#define KD 128    // 16 k * 8 d complex channels
#define KP 320    // doubled K (re/im interleaved)
#define PLANE_U 3276800   // uints per plane of B/T (128*160*160)
#define NBUCK 4096        // 2^12 morton buckets (4 bits/axis)
#define TWO_PI_F 6.28318530717958647692f

// T is scaled by TSCALE at stage1 (folded into alpha) so f16 T values sit in
// the normal range (~5e-3 instead of ~2e-5 subnormal); sampler undoes it.
#define TSCALE 256.0f
#define TSCALE_INV 0.00390625f

typedef __attribute__((ext_vector_type(8))) short bf16x8;   // 4 VGPRs, 8 bf16
typedef __attribute__((ext_vector_type(4))) float f32x4;
typedef _Float16 half2t __attribute__((ext_vector_type(2)));
typedef __fp16 fp16x2 __attribute__((ext_vector_type(2)));

__device__ __forceinline__ unsigned short f2bf(float x) {
    unsigned u = __float_as_uint(x);
    unsigned r = (u + 0x7FFFu + ((u >> 16) & 1u)) >> 16;   // RNE
    return (unsigned short)r;
}
__device__ __forceinline__ unsigned int packbf(float re, float im) {
    union { __hip_bfloat162 h; unsigned int u; } cv;
    cv.h = __float22bfloat162_rn(make_float2(re, im));      // v_cvt_pk_bf16_f32
    return cv.u;
}
// pack (a,b) f32 -> f16x2 in one v_cvt_pkrtz_f16_f32 (as half2t via bitcast)
__device__ __forceinline__ half2t cvtpk(float a, float b) {
    union { fp16x2 f; half2t h; } cv;
    cv.f = __builtin_amdgcn_cvt_pkrtz(a, b);
    return cv.h;
}
__device__ __forceinline__ unsigned int packh(float re, float im) {
    union { fp16x2 f; unsigned int u; } cv;
    cv.f = __builtin_amdgcn_cvt_pkrtz(re, im);
    return cv.u;
}
__device__ __forceinline__ half2t u2h2(unsigned int u) {
    union { unsigned int u; half2t h; } cv;
    cv.u = u;
    return cv.h;
}
// 2-way f16 dot with f32 accumulate: acc += a.x*b.x + a.y*b.y
__device__ __forceinline__ float fdot2h(half2t a, half2t b, float acc) {
#if __has_builtin(__builtin_amdgcn_fdot2)
    return __builtin_amdgcn_fdot2(a, b, acc, false);
#else
    return acc + (float)a.x * (float)b.x + (float)a.y * (float)b.y;
#endif
}
// Wim fragment uint from Wre fragment uint: (c,-s) -> (s,c)
__device__ __forceinline__ unsigned int wim_of(unsigned int u) {
    return ((u << 16) | (u >> 16)) ^ 0x00008000u;
}
__device__ __forceinline__ unsigned part1by2(unsigned x) {
    x &= 0x3FF;
    x = (x | (x << 16)) & 0xFF0000FFu;
    x = (x | (x << 8))  & 0x0300F00Fu;
    x = (x | (x << 4))  & 0x030C30C3u;
    x = (x | (x << 2))  & 0x09249249u;
    return x;
}
__device__ __forceinline__ unsigned morton_key(float x, float y, float z) {
    int cx = min(max((int)((x + 1.0f) * 8.0f), 0), 15);
    int cy = min(max((int)((y + 1.0f) * 8.0f), 0), 15);
    int cz = min(max((int)((z + 1.0f) * 8.0f), 0), 15);
    return part1by2(cx) | (part1by2(cy) << 1) | (part1by2(cz) << 2);   // 12 bits
}

// ---------------------------------------------------------------------------
// Fused preprocessing: [0,16) zero counts | [16,216) W init | [216,1816) packw
// ---------------------------------------------------------------------------
__global__ __launch_bounds__(256) void k_prep(
    const float* __restrict__ Pw_re, const float* __restrict__ Pw_im,
    unsigned int* __restrict__ Apw, unsigned short* __restrict__ Wre,
    unsigned int* __restrict__ counts)
{
    __shared__ unsigned int sT[64 * 33];
    int b = blockIdx.x;
    int tid = threadIdx.x;
    if (b < 16) {
        counts[b * 256 + tid] = 0;
        return;
    }
    if (b < 216) {
        int idx = (b - 16) * 256 + tid;   // < 51200
        int r = idx / KP, kp = idx - r * KP;
        int q = kp >> 1;
        int m = (r * q) % G;
        float th = (float)m * (TWO_PI_F / (float)G);
        float s, c;
        __sincosf(th, &s, &c);
        Wre[idx] = f2bf(((kp & 1) == 0 ? c : -s) * (1.0f / (float)G));
        return;
    }
    // packw: Pw (k,y,x,d) [204800, 8, 1280, 1] -> Apw[m=(k*8+d)*160+y][q=x]
    int b2 = b - 216;                     // 0..1599
    int k  = b2 / 100;
    int rem = b2 - k * 100;
    int pc = rem / 5;
    int q0 = (rem - pc * 5) * 32;

    int i = tid & 63, qo = tid >> 6;
    size_t base = (size_t)k * 204800 + (size_t)pc * 64 + i;
    #pragma unroll
    for (int qc = 0; qc < 8; qc++) {
        int q = q0 + qo * 8 + qc;
        float r  = Pw_re[base + (size_t)q * 1280];
        float im = Pw_im[base + (size_t)q * 1280];
        sT[i * 33 + qo * 8 + qc] = packbf(r, im);
    }
    __syncthreads();
    int qp = tid & 31, mo = tid >> 5;
    #pragma unroll
    for (int mc = 0; mc < 8; mc++) {
        int m = (k * 8 + mo) * G + pc * 8 + mc;
        Apw[(size_t)m * G + q0 + qp] = sT[(mc * 8 + mo) * 33 + qp];
    }
}

// ---------------------------------------------------------------------------
// Morton counting sort: hist -> scan -> scatter(sorted float4)
// ---------------------------------------------------------------------------
__global__ __launch_bounds__(256) void k_hist(
    const float* __restrict__ xyz, const float* __restrict__ bound,
    unsigned int* __restrict__ counts, int N)
{
    int i = blockIdx.x * blockDim.x + threadIdx.x;
    if (i >= N) return;
    float invb = 1.0f / bound[0];
    float x = xyz[3 * i + 0] * invb;
    float y = xyz[3 * i + 1] * invb;
    float z = xyz[3 * i + 2] * invb;
    atomicAdd(&counts[morton_key(x, y, z)], 1u);
}

// Shuffle-based scan: wave-scan (no barriers) + 16-wave LDS combine.
__global__ __launch_bounds__(1024) void k_scan(
    const unsigned int* __restrict__ counts,
    unsigned int* __restrict__ cursors)
{
    __shared__ unsigned int ws[16];
    int t = threadIdx.x;
    int lane = t & 63, wid = t >> 6;
    unsigned int local[4];
    unsigned int s = 0;
    #pragma unroll
    for (int i = 0; i < 4; i++) { local[i] = counts[t * 4 + i]; s += local[i]; }
    unsigned int sl = s;                    // own group-of-4 sum
    #pragma unroll
    for (int off = 1; off < 64; off <<= 1) {
        unsigned int v = __shfl_up(s, off, 64);
        if (lane >= off) s += v;            // inclusive wave scan
    }
    if (lane == 63) ws[wid] = s;
    __syncthreads();
    if (t < 16) {
        unsigned int x = ws[t];
        #pragma unroll
        for (int off = 1; off < 16; off <<= 1) {
            unsigned int v = __shfl_up(x, off, 64);
            if (t >= off) x += v;
        }
        ws[t] = x;                          // inclusive over wave totals
    }
    __syncthreads();
    unsigned int run = s - sl + (wid > 0 ? ws[wid - 1] : 0u);
    #pragma unroll
    for (int i = 0; i < 4; i++) { cursors[t * 4 + i] = run; run += local[i]; }
}

__global__ __launch_bounds__(256) void k_scatter(
    const float* __restrict__ xyz, const float* __restrict__ bound,
    unsigned int* __restrict__ cursors, float4* __restrict__ sxyz, int N)
{
    int i = blockIdx.x * blockDim.x + threadIdx.x;
    if (i >= N) return;
    float invb = 1.0f / bound[0];
    float x = xyz[3 * i + 0] * invb;
    float y = xyz[3 * i + 1] * invb;
    float z = xyz[3 * i + 2] * invb;
    unsigned int pos = atomicAdd(&cursors[morton_key(x, y, z)], 1u);
    sxyz[pos] = make_float4(x, y, z, __int_as_float(i));
}

// ---------------------------------------------------------------------------
// Stage 1 (proven R4 config): B[m=(kd,p)][l] = alpha * sum_q A*W[l][q].
// Wave = 2 m-tiles x 2 l-tiles per t-step (8 independent MFMA chains).
// W staged once per block into 100KB LDS, pre-permuted to fragment order
// sW[(lt*10+t)*64+lane] (lane-contiguous ds_read_b128, conflict-free).
// ---------------------------------------------------------------------------
__global__ __launch_bounds__(512) void k_stage1(
    const float* __restrict__ Pu_re, const float* __restrict__ Pu_im,
    const float* __restrict__ Pv_re, const float* __restrict__ Pv_im,
    const unsigned int* __restrict__ Apw,
    const float* __restrict__ alpha_params,
    const unsigned short* __restrict__ Wre,
    unsigned int* __restrict__ Bfrag)
{
    __shared__ __align__(16) unsigned short sW[51200];   // 100 KB permuted W
    int tid = threadIdx.x;
    int w = tid >> 6, lane = tid & 63;
    int col = lane & 15, g4 = lane >> 4;
    int gw = blockIdx.x * 8 + w;          // 0..1919 wave-tasks
    int mt0 = gw * 2;                     // global m-tile pair
    int plane = mt0 / 1280;
    int mtl0 = mt0 - plane * 1280;        // plane-local tile idx (even)

    // stage W permuted: chunk=(lt*10+t)*64+ln holds Wre frag of (lt,t,ln)
    for (int chunk = tid; chunk < 6400; chunk += 512) {
        int lt = chunk / 640;
        int r  = chunk - lt * 640;
        int t  = r >> 6;
        int ln = r & 63;
        int c  = ln & 15, g = ln >> 4;
        uint4 v = *(const uint4*)&Wre[(lt * 16 + c) * KP + t * 32 + g * 8];
        *(uint4*)&sW[chunk * 8] = v;
    }

    float ap = alpha_params[0];
    float bxv = 10.0f * ap;
    float alpha = (bxv > 1.0f) ? ap : log1pf(expf(fminf(bxv, 1.0f))) * 0.1f;
    alpha *= TSCALE;

    bf16x8 afr[2][10];
    #pragma unroll
    for (int ti = 0; ti < 2; ti++) {
        int mtl = mtl0 + ti;
        if (plane == 2) {
            const unsigned int* a2 = Apw + (size_t)(mtl * 16 + col) * G + g4 * 4;
            #pragma unroll
            for (int t = 0; t < 10; t++) {
                union { uint4 u; bf16x8 b; } cv;
                cv.u = *(const uint4*)(a2 + t * 16);
                afr[ti][t] = cv.b;
            }
        } else {
            const float *Ar, *Ai; int sd_, sp_;
            if (plane == 0) { Ar = Pu_re; Ai = Pu_im; sd_ = 25600; sp_ = 160; }
            else            { Ar = Pv_re; Ai = Pv_im; sd_ = 160;   sp_ = 1280; }
            int m = mtl * 16 + col;
            int k = m / 1280; int rm = m - k * 1280;
            int d = rm / 160; int p = rm - d * 160;
            size_t abase = (size_t)k * 204800 + (size_t)d * sd_ + (size_t)p * sp_ + g4 * 4;
            #pragma unroll
            for (int t = 0; t < 10; t++) {
                float4 vr = *(const float4*)(Ar + abase + t * 16);
                float4 vi = *(const float4*)(Ai + abase + t * 16);
                union { unsigned int u[4]; bf16x8 b; } cv;
                cv.u[0] = packbf(vr.x, vi.x); cv.u[1] = packbf(vr.y, vi.y);
                cv.u[2] = packbf(vr.z, vi.z); cv.u[3] = packbf(vr.w, vi.w);
                afr[ti][t] = cv.b;
            }
        }
    }

    __syncthreads();

    unsigned int* Bpl = Bfrag + (size_t)plane * PLANE_U;
    int kd0 = mtl0 / 10, pt0 = mtl0 - kd0 * 10;
    int mtl1 = mtl0 + 1;
    int kd1 = mtl1 / 10, pt1 = mtl1 - kd1 * 10;

    for (int lt2 = 0; lt2 < 5; lt2++) {
        int ltA = lt2 * 2, ltB = lt2 * 2 + 1;
        // acc[tile][lt-half] re/im — 8 independent MFMA chains
        f32x4 arA0 = (f32x4)(0.f), aiA0 = (f32x4)(0.f);
        f32x4 arA1 = (f32x4)(0.f), aiA1 = (f32x4)(0.f);
        f32x4 arB0 = (f32x4)(0.f), aiB0 = (f32x4)(0.f);
        f32x4 arB1 = (f32x4)(0.f), aiB1 = (f32x4)(0.f);
        const unsigned short* wpA = &sW[(ltA * 640 + lane) * 8];
        const unsigned short* wpB = &sW[(ltB * 640 + lane) * 8];
        #pragma unroll
        for (int t = 0; t < 10; t++) {
            union { uint4 u; bf16x8 b; } crA, ciA, crB, ciB;
            crA.u = *(const uint4*)(wpA + t * 512);
            crB.u = *(const uint4*)(wpB + t * 512);
            ciA.u.x = wim_of(crA.u.x); ciA.u.y = wim_of(crA.u.y);
            ciA.u.z = wim_of(crA.u.z); ciA.u.w = wim_of(crA.u.w);
            ciB.u.x = wim_of(crB.u.x); ciB.u.y = wim_of(crB.u.y);
            ciB.u.z = wim_of(crB.u.z); ciB.u.w = wim_of(crB.u.w);
            arA0 = __builtin_amdgcn_mfma_f32_16x16x32_bf16(afr[0][t], crA.b, arA0, 0, 0, 0);
            aiA0 = __builtin_amdgcn_mfma_f32_16x16x32_bf16(afr[0][t], ciA.b, aiA0, 0, 0, 0);
            arB0 = __builtin_amdgcn_mfma_f32_16x16x32_bf16(afr[0][t], crB.b, arB0, 0, 0, 0);
            aiB0 = __builtin_amdgcn_mfma_f32_16x16x32_bf16(afr[0][t], ciB.b, aiB0, 0, 0, 0);
            arA1 = __builtin_amdgcn_mfma_f32_16x16x32_bf16(afr[1][t], crA.b, arA1, 0, 0, 0);
            aiA1 = __builtin_amdgcn_mfma_f32_16x16x32_bf16(afr[1][t], ciA.b, aiA1, 0, 0, 0);
            arB1 = __builtin_amdgcn_mfma_f32_16x16x32_bf16(afr[1][t], crB.b, arB1, 0, 0, 0);
            aiB1 = __builtin_amdgcn_mfma_f32_16x16x32_bf16(afr[1][t], ciB.b, aiB1, 0, 0, 0);
        }
        uint4 o;
        o.x = packbf(alpha * arA0[0], alpha * aiA0[0]);
        o.y = packbf(alpha * arA0[1], alpha * aiA0[1]);
        o.z = packbf(alpha * arA0[2], alpha * aiA0[2]);
        o.w = packbf(alpha * arA0[3], alpha * aiA0[3]);
        *(uint4*)(Bpl + (size_t)(kd0 * 10 + ltA) * 2560 + pt0 * 256 + lane * 4) = o;
        o.x = packbf(alpha * arB0[0], alpha * aiB0[0]);
        o.y = packbf(alpha * arB0[1], alpha * aiB0[1]);
        o.z = packbf(alpha * arB0[2], alpha * aiB0[2]);
        o.w = packbf(alpha * arB0[3], alpha * aiB0[3]);
        *(uint4*)(Bpl + (size_t)(kd0 * 10 + ltB) * 2560 + pt0 * 256 + lane * 4) = o;
        o.x = packbf(alpha * arA1[0], alpha * aiA1[0]);
        o.y = packbf(alpha * arA1[1], alpha * aiA1[1]);
        o.z = packbf(alpha * arA1[2], alpha * aiA1[2]);
        o.w = packbf(alpha * arA1[3], alpha * aiA1[3]);
        *(uint4*)(Bpl + (size_t)(kd1 * 10 + ltA) * 2560 + pt1 * 256 + lane * 4) = o;
        o.x = packbf(alpha * arB1[0], alpha * aiB1[0]);
        o.y = packbf(alpha * arB1[1], alpha * aiB1[1]);
        o.z = packbf(alpha * arB1[2], alpha * aiB1[2]);
        o.w = packbf(alpha * arB1[3], alpha * aiB1[3]);
        *(uint4*)(Bpl + (size_t)(kd1 * 10 + ltB) * 2560 + pt1 * 256 + lane * 4) = o;
    }
}

// ---------------------------------------------------------------------------
// Stage 2: T[j][l][kd] = sum_p W[j][p]*B[kd][p][l].
// Block = (kd-octet, l-tile, plane), 640 thr = 10 waves = 10 j-tiles.
// B octet staged once into 80KB LDS; W A-frags register-hoisted.
// T packed f16 (re,im) per uint — consumed by v_dot2_f32_f16 in sampler.
// ---------------------------------------------------------------------------
__global__ __launch_bounds__(640) void k_stage2(
    const unsigned int* __restrict__ Bfrag,
    const unsigned short* __restrict__ Wre,
    unsigned int* __restrict__ Tall)
{
    __shared__ __align__(16) unsigned int sB[20480];   // 80 KB: 8 kd x 2560
    int tid = threadIdx.x;
    int w = tid >> 6, lane = tid & 63;
    int col = lane & 15, g4 = lane >> 4;
    int kdo = blockIdx.x;
    int lt  = blockIdx.y;
    int plane = blockIdx.z;

    const unsigned int* Bp = Bfrag + (size_t)plane * PLANE_U;
    #pragma unroll
    for (int i = 0; i < 8; i++) {
        uint4 v = *(const uint4*)(Bp + ((size_t)(kdo * 8 + i) * 10 + lt) * 2560 + tid * 4);
        *(uint4*)(sB + i * 2560 + tid * 4) = v;
    }

    bf16x8 wfr[10];
    const unsigned short* wp = &Wre[(w * 16 + col) * KP + g4 * 8];
    #pragma unroll
    for (int t = 0; t < 10; t++)
        wfr[t] = *(const bf16x8*)(wp + t * 32);

    __syncthreads();

    f32x4 ar[8], ai[8];
    #pragma unroll
    for (int i = 0; i < 8; i++) { ar[i] = (f32x4)(0.f); ai[i] = (f32x4)(0.f); }

    #pragma unroll
    for (int t = 0; t < 10; t++) {
        union { bf16x8 b; uint4 u; } cr, ci;
        cr.b = wfr[t];
        ci.u.x = wim_of(cr.u.x); ci.u.y = wim_of(cr.u.y);
        ci.u.z = wim_of(cr.u.z); ci.u.w = wim_of(cr.u.w);
        #pragma unroll
        for (int kq = 0; kq < 8; kq++) {
            bf16x8 bf = *(const bf16x8*)&sB[kq * 2560 + (t * 64 + lane) * 4];
            ar[kq] = __builtin_amdgcn_mfma_f32_16x16x32_bf16(cr.b, bf, ar[kq], 0, 0, 0);
            ai[kq] = __builtin_amdgcn_mfma_f32_16x16x32_bf16(ci.b, bf, ai[kq], 0, 0, 0);
        }
    }

    unsigned int* Tp = Tall + (size_t)plane * PLANE_U;
    #pragma unroll
    for (int reg = 0; reg < 4; reg++) {
        int j = w * 16 + g4 * 4 + reg;
        int l = lt * 16 + col;
        uint4 o0, o1;
        o0.x = packh(ar[0][reg], ai[0][reg]);
        o0.y = packh(ar[1][reg], ai[1][reg]);
        o0.z = packh(ar[2][reg], ai[2][reg]);
        o0.w = packh(ar[3][reg], ai[3][reg]);
        o1.x = packh(ar[4][reg], ai[4][reg]);
        o1.y = packh(ar[5][reg], ai[5][reg]);
        o1.z = packh(ar[6][reg], ai[6][reg]);
        o1.w = packh(ar[7][reg], ai[7][reg]);
        size_t ta = ((size_t)(j * G + l)) * KD + kdo * 8;
        *(uint4*)(Tp + ta)     = o0;
        *(uint4*)(Tp + ta + 4) = o1;
    }
}

// ---------------------------------------------------------------------------
// Sampler, 3 per-plane passes (R5 theory: T=37.5MB > 32MB L2 aggregate ->
// corner-row reads served from L3; one 12.5MB plane per pass fits L2,
// ~3.1MB per XCD-octant with the seg swizzle). Pass 0 '=', passes 1,2 '+='.
// plane_addr/plane_math unchanged (proven path).
// ---------------------------------------------------------------------------
__device__ __forceinline__ void plane_addr(const unsigned int* __restrict__ T,
    float gy, float gx, int k, const unsigned int** cp, float* wv)
{
    float iy = (gy + 1.0f) * (0.5f * (float)GM1);
    float ix = (gx + 1.0f) * (0.5f * (float)GM1);
    float iy0f = floorf(iy), ix0f = floorf(ix);
    float wy = iy - iy0f, wx = ix - ix0f;
    int iy0 = (int)iy0f, ix0 = (int)ix0f;
    int iy1 = min(iy0 + 1, GM1), ix1 = min(ix0 + 1, GM1);
    iy0 = max(min(iy0, GM1), 0); ix0 = max(min(ix0, GM1), 0);
    iy1 = max(iy1, 0); ix1 = max(ix1, 0);
    cp[0] = &T[(size_t)(iy0 * G + ix0) * KD + k * 8];
    cp[1] = &T[(size_t)(iy0 * G + ix1) * KD + k * 8];
    cp[2] = &T[(size_t)(iy1 * G + ix0) * KD + k * 8];
    cp[3] = &T[(size_t)(iy1 * G + ix1) * KD + k * 8];
    wv[0] = (1.f - wx) * (1.f - wy);
    wv[1] = wx * (1.f - wy);
    wv[2] = (1.f - wx) * wy;
    wv[3] = wx * wy;
}

__device__ __forceinline__ float plane_math(const uint4* va, const uint4* vb,
                                            const float* wv, float fc)
{
    float s1v, c1v;
    __sincosf(TWO_PI_F * fc, &s1v, &c1v);
    // trig weights (C'_d, -S'_d) as f16 pairs; d=0: (1,0); d>=1: (2cd, -2sd)
    half2t tw[8];
    tw[0] = u2h2(0x00003C00u);            // (1.0h, 0.0h)
    float cd = c1v, sd = s1v;
    tw[1] = cvtpk(cd + cd, -(sd + sd));
    #pragma unroll
    for (int d = 2; d < 8; d++) {
        float t2 = cd + cd;
        float cn = __builtin_fmaf(t2, cd, -1.0f);
        float sn = t2 * sd;
        cd = cn; sd = sn;
        tw[d] = cvtpk(cd + cd, -(sd + sd));
    }
    const unsigned int* a0 = (const unsigned int*)&va[0];
    const unsigned int* a1 = (const unsigned int*)&va[1];
    const unsigned int* a2 = (const unsigned int*)&va[2];
    const unsigned int* a3 = (const unsigned int*)&va[3];
    const unsigned int* b0 = (const unsigned int*)&vb[0];
    const unsigned int* b1 = (const unsigned int*)&vb[1];
    const unsigned int* b2 = (const unsigned int*)&vb[2];
    const unsigned int* b3 = (const unsigned int*)&vb[3];
    float d0 = 0.f, d1 = 0.f, d2 = 0.f, d3 = 0.f;   // 4 independent chains
    #pragma unroll
    for (int d = 0; d < 4; d++) {
        half2t t = tw[d];
        d0 = fdot2h(u2h2(a0[d]), t, d0);
        d1 = fdot2h(u2h2(a1[d]), t, d1);
        d2 = fdot2h(u2h2(a2[d]), t, d2);
        d3 = fdot2h(u2h2(a3[d]), t, d3);
    }
    #pragma unroll
    for (int d = 0; d < 4; d++) {
        half2t t = tw[d + 4];
        d0 = fdot2h(u2h2(b0[d]), t, d0);
        d1 = fdot2h(u2h2(b1[d]), t, d1);
        d2 = fdot2h(u2h2(b2[d]), t, d2);
        d3 = fdot2h(u2h2(b3[d]), t, d3);
    }
    float acc = wv[0] * d0;
    acc = __builtin_fmaf(wv[1], d1, acc);
    acc = __builtin_fmaf(wv[2], d2, acc);
    acc = __builtin_fmaf(wv[3], d3, acc);
    return acc;
}

template<int PL>
__global__ __launch_bounds__(256) void k_sample1(
    const float4* __restrict__ sxyz,
    const unsigned int* __restrict__ T,
    float* __restrict__ out, int N)
{
    int tid = threadIdx.x;
    int k = tid & 15;
    int nblocks = (N + 15) / 16;
    int seg = blockIdx.x & 7;
    int segblocks = nblocks >> 3;                 // N multiple of 128
    int pid = (seg * segblocks + (blockIdx.x >> 3)) * 16 + (tid >> 4);
    if (pid >= N) return;

    float4 pw = sxyz[pid];
    int n = __float_as_int(pw.w);
    float x = pw.x, y = pw.y, z = pw.z;

    float gy, gx, fc;
    if (PL == 0)      { gy = y; gx = z; fc = (x + 1.0f) * 0.5f; }
    else if (PL == 1) { gy = x; gx = z; fc = (y + 1.0f) * 0.5f; }
    else              { gy = y; gx = x; fc = (z + 1.0f) * 0.5f; }

    const unsigned int* cp[4];
    float wv[4];
    plane_addr(T, gy, gx, k, cp, wv);

    uint4 va[4], vb[4];
    #pragma unroll
    for (int c = 0; c < 4; c++) {
        va[c] = *(const uint4*)cp[c];
        vb[c] = *(const uint4*)(cp[c] + 4);
    }

    float acc = plane_math(va, vb, wv, fc) * TSCALE_INV;
    if (PL == 0) out[n * 16 + k] = acc;
    else         out[n * 16 + k] += acc;
}

// ---------------------------------------------------------------------------
extern "C" void kernel_launch(void* const* d_in, const int* in_sizes, int n_in,
                              void* d_out, int out_size, void* d_ws, size_t ws_size,
                              hipStream_t stream) {
    const float* xyz          = (const float*)d_in[0];
    const float* bound        = (const float*)d_in[1];
    const float* alpha_params = (const float*)d_in[2];
    const float* Pu_re = (const float*)d_in[3];
    const float* Pu_im = (const float*)d_in[4];
    const float* Pv_re = (const float*)d_in[5];
    const float* Pv_im = (const float*)d_in[6];
    const float* Pw_re = (const float*)d_in[7];
    const float* Pw_im = (const float*)d_in[8];
    float* out = (float*)d_out;
    int N = in_sizes[0] / 3;

    // ws: Wre 100K | Apw 12.5M | Bfrag 37.5M | T 37.5M | counts 16K |
    //     cursors 16K | sxyz 2M
    char* ws = (char*)d_ws;
    unsigned short* Wre  = (unsigned short*)(ws);
    unsigned int*   Apw  = (unsigned int*)(ws + 102400);
    unsigned int*   Bfr  = (unsigned int*)(ws + 102400 + 13107200);
    unsigned int*   Tall = (unsigned int*)(ws + 102400 + 13107200 + 39321600);
    char*           ws2  = ws + 102400 + 13107200 + 39321600 + 39321600;
    unsigned int*   counts  = (unsigned int*)(ws2);
    unsigned int*   cursors = (unsigned int*)(ws2 + 16384);
    float4*         sxyz    = (float4*)(ws2 + 32768);
    unsigned int*   Tu   = Tall;
    unsigned int*   Tv   = Tall + (size_t)PLANE_U;
    unsigned int*   Tw   = Tall + (size_t)2 * PLANE_U;

    // fused prep: zero counts + W table + Pw pack
    k_prep<<<1816, 256, 0, stream>>>(Pw_re, Pw_im, Apw, Wre, counts);
    // sort chain
    k_hist<<<(N + 255) / 256, 256, 0, stream>>>(xyz, bound, counts, N);
    k_scan<<<1, 1024, 0, stream>>>(counts, cursors);
    k_scatter<<<(N + 255) / 256, 256, 0, stream>>>(xyz, bound, cursors, sxyz, N);
    // DFT pipeline
    k_stage1<<<240, 512, 0, stream>>>(Pu_re, Pu_im, Pv_re, Pv_im, Apw,
                                      alpha_params, Wre, Bfr);
    k_stage2<<<dim3(16, 10, 3), 640, 0, stream>>>(Bfr, Wre, Tall);
    // sampler: one plane per pass (L2-resident working set)
    int sgrid = (N + 15) / 16;
    k_sample1<0><<<sgrid, 256, 0, stream>>>(sxyz, Tu, out, N);
    k_sample1<1><<<sgrid, 256, 0, stream>>>(sxyz, Tv, out, N);
    k_sample1<2><<<sgrid, 256, 0, stream>>>(sxyz, Tw, out, N);
}